// Round 1
// baseline (2410.713 us; speedup 1.0000x reference)
//
#include <hip/hip_runtime.h>

// Multi-layer tanh RNN, layer-pipelined persistent kernel.
// R17 = R16 (1372us) + BC=32/NB=16: grid 320 -> 160 blocks, 1 block/CU.
//  Theory: with 320 blocks, layers 8-9 (blockIdx 256-319) were second-resident
//  on CUs already running layers 0-1; the pipeline's rate = slowest stage, so
//  every stage ran at shared-CU speed. Also the ~4k cycles/step of fixed
//  overhead (barriers, staging, flag amortization, tanh chain) now amortizes
//  over 2x batch rows per step. Co-XCD chunk chains preserved automatically:
//  (l*16+c)%8 == c%8, all layers of a chunk land on one XCD.
//  Structure otherwise identical to R16: bf16 LDS state, fp32 ring, 2-plane
//  weights, deferred stores, K=RD/2 adaptive ring depth.
//  New: 2 M-tiles per wave (rows mt*16..mt*16+15), acc[2][2], 16 h/thread,
//  layer-9 dot re-split as 8 threads x 13 elems per row, launch_bounds(256,1).

#define HH   100   // hidden
#define HS   132   // padded fp32 stride (bias etc.)
#define HSS  136   // bf16 LDS row stride in shorts (272B = 17*16, b128-aligned)
#define NL   10    // layers
#define BBS  512   // batch
#define TTS  512   // time
#define NB   16    // batch chunks
#define BC   32    // batch per chunk
#define NT   256   // threads per block

typedef __attribute__((ext_vector_type(8))) short short8;
typedef __attribute__((ext_vector_type(4))) float f32x4;
typedef __attribute__((ext_vector_type(2))) unsigned int u32x2;

__global__ void init_ws_kernel(int* wsi) {
  int i = blockIdx.x * blockDim.x + threadIdx.x;
  if (i < 16384) wsi[i] = 0;   // zero both flag regions (64KB)
}

__device__ __forceinline__ int flag_idx(int iface, int chunk) {
  return (iface * NB + chunk) * 16;
}

__device__ __forceinline__ void lds_barrier() {
  __asm__ __volatile__("s_waitcnt lgkmcnt(0)\n\ts_barrier" ::: "memory");
}
__device__ __forceinline__ void ctl_barrier() {
  __asm__ __volatile__("s_barrier" ::: "memory");
}

__device__ __forceinline__ float fast_tanh(float v) {
  float e = __expf(2.0f * v);
  return 1.0f - 2.0f * __builtin_amdgcn_rcpf(e + 1.0f);
}

__device__ __forceinline__ unsigned short bf_rtn(float x) {
  return (unsigned short)((__float_as_uint(x) + 0x8000u) >> 16);
}
__device__ __forceinline__ unsigned pack_rtn(float x0, float x1) {
  unsigned u0 = __float_as_uint(x0) + 0x8000u;
  unsigned u1 = __float_as_uint(x1) + 0x8000u;
  return (u0 >> 16) | (u1 & 0xFFFF0000u);
}
// f32x4 -> 4 bf16 packed in 8 bytes
__device__ __forceinline__ u32x2 pack4(f32x4 q) {
  u32x2 d;
  d[0] = pack_rtn(q[0], q[1]);
  d[1] = pack_rtn(q[2], q[3]);
  return d;
}

__global__ __launch_bounds__(NT, 1) void rnn_pipe(
    const float* __restrict__ x,     // [B,T,1]
    const float* __restrict__ h0,    // [L,B,H]
    const float* __restrict__ Wih0,  // [H,1]
    const float* __restrict__ Wih,   // [L-1,H,H]
    const float* __restrict__ Whh,   // [L,H,H]
    const float* __restrict__ bih,   // [L,H]
    const float* __restrict__ bhh,   // [L,H]
    const float* __restrict__ Wout,  // [1,H]
    const float* __restrict__ bout,  // [1]
    float* __restrict__ out,         // [B*T] outs ++ [L*B*H] h_final
    float* __restrict__ ring,
    int*   __restrict__ wsi,
    int Kv, int RDv)
{
  const int layer = blockIdx.x / NB;
  const int chunk = blockIdx.x % NB;
  const int tid   = threadIdx.x;
  const int Km = Kv - 1, RDm = RDv - 1;
  const int NE = BC * HH;  // 3200 elements per activation slot

  const int wave = tid >> 6, lane = tid & 63;
  const int quad = lane >> 4, lp = lane & 15;

  // LDS: 2 * (2*32*136*2) = 34.8KB state + ~2KB consts
  __shared__ unsigned short hbuf[2][BC][HSS];  // recurrent state bf16
  __shared__ unsigned short ibuf[2][BC][HSS];  // staged prev-layer input bf16
  __shared__ float bias[HS];
  __shared__ float wi0s[HS];
  __shared__ float wouts[HS];
  __shared__ float xin[2][BC];

  // ---- one-time LDS init ----
  for (int i = tid; i < 2 * BC * HSS; i += NT) {
    (&hbuf[0][0][0])[i] = 0; (&ibuf[0][0][0])[i] = 0;
  }
  for (int i = tid; i < HS; i += NT) {
    bias[i]  = (i < HH) ? (bih[layer * HH + i] + bhh[layer * HH + i]) : 0.f;
    wi0s[i]  = (i < HH) ? Wih0[i] : 0.f;
    wouts[i] = (i < HH) ? Wout[i] : 0.f;
  }
  if (tid < BC) { xin[0][tid] = 0.f; xin[1][tid] = 0.f; }
  __syncthreads();
  for (int idx = tid; idx < NE; idx += NT)
    hbuf[0][idx / HH][idx % HH] =
        bf_rtn(h0[((size_t)layer * BBS + chunk * BC + idx / HH) * HH + idx % HH]);
  __syncthreads();

  // ---- B-fragments in registers: fused W = [Whh (k 0..99) ; Wih (k 128..227)]
  // 2-plane (weight precision kept), 128 regs (compiler may place in AGPRs).
  short8 Bf[8][2][2];
  #pragma unroll
  for (int kc = 0; kc < 8; ++kc) {
    #pragma unroll
    for (int ntl = 0; ntl < 2; ++ntl) {
      const int n = wave * 32 + ntl * 16 + lp;
      float wv[8];
      #pragma unroll
      for (int j = 0; j < 8; ++j) {
        const int k = kc * 32 + quad * 8 + j;
        float w = 0.f;
        if (kc < 4) {
          if (k < HH && n < HH) w = Whh[(size_t)layer * HH * HH + n * HH + k];
        } else {
          const int kk = k - 128;
          if (layer > 0 && kk >= 0 && kk < HH && n < HH)
            w = Wih[(size_t)(layer - 1) * HH * HH + n * HH + kk];
        }
        wv[j] = w;
      }
      // plane1 = truncate, plane2 = residual (exact split)
      __attribute__((ext_vector_type(4))) unsigned int p1, p2;
      #pragma unroll
      for (int j2 = 0; j2 < 4; ++j2) {
        unsigned ua = __float_as_uint(wv[2 * j2]), ub = __float_as_uint(wv[2 * j2 + 1]);
        p1[j2] = (ua >> 16) | (ub & 0xFFFF0000u);
        float ra = wv[2 * j2]     - __uint_as_float(ua & 0xFFFF0000u);
        float rb = wv[2 * j2 + 1] - __uint_as_float(ub & 0xFFFF0000u);
        p2[j2] = (__float_as_uint(ra) >> 16) | (__float_as_uint(rb) & 0xFFFF0000u);
      }
      Bf[kc][ntl][0] = __builtin_bit_cast(short8, p1);
      Bf[kc][ntl][1] = __builtin_bit_cast(short8, p2);
    }
  }

  // ---- flags / ring pointers (R8-proven protocol, agent scope) ----
  int* prog_in  = (layer > 0)      ? wsi + flag_idx(layer - 1, chunk)        : nullptr;
  int* cons_in  = (layer > 0)      ? wsi + 8192 + flag_idx(layer - 1, chunk) : nullptr;
  int* prog_out = (layer < NL - 1) ? wsi + flag_idx(layer, chunk)            : nullptr;
  int* cons_out = (layer < NL - 1) ? wsi + 8192 + flag_idx(layer, chunk)     : nullptr;
  const size_t slot_sz = (size_t)NE;  // 3200 floats
  float* ring_in  = (layer > 0)      ? ring + (size_t)((layer - 1) * NB + chunk) * RDv * slot_sz : nullptr;
  float* ring_out = (layer < NL - 1) ? ring + (size_t)(layer * NB + chunk) * RDv * slot_sz       : nullptr;

  const int jcv[2] = { wave * 32 + lp, wave * 32 + 16 + lp };   // C columns
  const float br[2]  = { bias[jcv[0]], bias[jcv[1]] };
  const float w0r[2] = { wi0s[jcv[0]], wi0s[jcv[1]] };
  const float boutv = bout[0];

  f32x4 hreg[2][2];          // step-t h values fp32 (deferred ring stores) [mt][ntl]
  float dso = 0.f;           // deferred layer-9 output
  float px = 0.f;
  bool have_ring_def = false, have_out_def = false;

  for (int t = 0; t < TTS; ++t) {
    const int par = t & 1, nxt = par ^ 1;
    const bool batch_start = (t & Km) == 0;
    const bool batch_last  = (t & Km) == Km;

    // ---- batch boundary: wait + exposed staging of slot t into parity par ----
    if (batch_start) {
      if (tid == 0) {
        if (layer > 0) {
          while (__hip_atomic_load(prog_in, __ATOMIC_RELAXED, __HIP_MEMORY_SCOPE_AGENT) < t + Kv)
            __builtin_amdgcn_s_sleep(1);
          (void)__hip_atomic_load(prog_in, __ATOMIC_ACQUIRE, __HIP_MEMORY_SCOPE_AGENT);
        }
        if (layer < NL - 1 && t + Kv > RDv) {
          while (__hip_atomic_load(cons_out, __ATOMIC_RELAXED, __HIP_MEMORY_SCOPE_AGENT) < t + Kv - RDv)
            __builtin_amdgcn_s_sleep(1);
        }
      }
      ctl_barrier();
      if (layer > 0) {
        const float* src = ring_in + (size_t)(t & RDm) * slot_sz;
        #pragma unroll
        for (int j = 0; j < 4; ++j) {
          const int i = tid * 4 + j * 1024;
          if (i < NE) {
            u32x2 d = pack4(*(const f32x4*)(src + i));
            *(u32x2*)&ibuf[par][i / HH][i % HH] = d;
          }
        }
      } else if (t == 0) {
        if (tid < BC) xin[0][tid] = x[(size_t)(chunk * BC + tid) * TTS];
      }
      lds_barrier();
    }

    // ---- issue deferred stores from step t-1 (stay in flight past barrier) ----
    if (have_ring_def) {
      float* dst = ring_out + (size_t)((t - 1) & RDm) * slot_sz;
      #pragma unroll
      for (int mt = 0; mt < 2; ++mt)
        #pragma unroll
        for (int ntl = 0; ntl < 2; ++ntl)
          if (jcv[ntl] < HH)
            #pragma unroll
            for (int r = 0; r < 4; ++r)
              dst[(size_t)(mt * 16 + quad * 4 + r) * HH + jcv[ntl]] = hreg[mt][ntl][r];
      have_ring_def = false;
    }
    if (have_out_def) {
      if ((tid & 7) == 0)
        out[(size_t)(chunk * BC + (tid >> 3)) * TTS + (t - 1)] = dso;
      have_out_def = false;
    }

    // ---- prefetch inp_{t+1} into regs (staged into ibuf[nxt] post-compute) ----
    f32x4 pr[4] = {};
    bool pre = false;
    if (layer > 0) {
      if (!batch_last && t + 1 < TTS) {
        const float* src = ring_in + (size_t)((t + 1) & RDm) * slot_sz;
        #pragma unroll
        for (int j = 0; j < 4; ++j) {
          const int i = tid * 4 + j * 1024;
          if (i < NE) pr[j] = *(const f32x4*)(src + i);
        }
        pre = true;
      }
    } else {
      if (t + 1 < TTS && tid < BC) px = x[(size_t)(chunk * BC + tid) * TTS + (t + 1)];
    }

    // ---- MFMA: A = direct bf16 ds_read_b128 (2 M-tiles), B 2-plane ----
    f32x4 acc[2][2] = {};
    f32x4 acc2[2][2] = {};
    auto mfma_kc = [&](f32x4 (*accp)[2], const unsigned short (*buf)[HSS], int koff, int bfi) {
      #pragma unroll
      for (int mt = 0; mt < 2; ++mt) {
        short8 A1 = *(const short8*)&buf[mt * 16 + lp][koff + quad * 8];
        #pragma unroll
        for (int ntl = 0; ntl < 2; ++ntl) {
          accp[mt][ntl] = __builtin_amdgcn_mfma_f32_16x16x32_bf16(
              A1, Bf[bfi][ntl][1], accp[mt][ntl], 0, 0, 0);   // a1*b2 (small first)
          accp[mt][ntl] = __builtin_amdgcn_mfma_f32_16x16x32_bf16(
              A1, Bf[bfi][ntl][0], accp[mt][ntl], 0, 0, 0);   // a1*b1
        }
      }
    };
    #pragma unroll
    for (int kc = 0; kc < 4; ++kc) mfma_kc(acc, hbuf[par], kc * 32, kc);
    if (layer > 0) {
      #pragma unroll
      for (int kc = 0; kc < 4; ++kc) mfma_kc(acc2, ibuf[par], kc * 32, kc + 4);
    }

    // ---- epilogue: merge, bias(+x*w0), tanh, pack bf16, write hbuf[nxt] ----
    #pragma unroll
    for (int mt = 0; mt < 2; ++mt)
      #pragma unroll
      for (int ntl = 0; ntl < 2; ++ntl) {
        #pragma unroll
        for (int r = 0; r < 4; ++r) {
          const int m = mt * 16 + quad * 4 + r;
          float v = acc[mt][ntl][r] + acc2[mt][ntl][r] + br[ntl];
          if (layer == 0) v += xin[par][m] * w0r[ntl];
          float h = fast_tanh(v);
          hreg[mt][ntl][r] = h;
          if (jcv[ntl] < HH) hbuf[nxt][m][jcv[ntl]] = bf_rtn(h);
        }
      }

    // batch-last ring store cannot be deferred past the flag publish
    if (layer < NL - 1 && batch_last) {
      float* dst = ring_out + (size_t)(t & RDm) * slot_sz;
      #pragma unroll
      for (int mt = 0; mt < 2; ++mt)
        #pragma unroll
        for (int ntl = 0; ntl < 2; ++ntl)
          if (jcv[ntl] < HH)
            #pragma unroll
            for (int r = 0; r < 4; ++r)
              dst[(size_t)(mt * 16 + quad * 4 + r) * HH + jcv[ntl]] = hreg[mt][ntl][r];
    }
    if (t == TTS - 1) {   // final hidden state, fp32-exact from registers
      #pragma unroll
      for (int mt = 0; mt < 2; ++mt)
        #pragma unroll
        for (int ntl = 0; ntl < 2; ++ntl)
          if (jcv[ntl] < HH)
            #pragma unroll
            for (int r = 0; r < 4; ++r)
              out[(size_t)BBS * TTS +
                  ((size_t)layer * BBS + chunk * BC + mt * 16 + quad * 4 + r) * HH + jcv[ntl]] =
                  hreg[mt][ntl][r];
    }

    // ---- stage prefetched inp_{t+1} into ibuf[nxt] / xin[nxt] ----
    if (pre) {
      #pragma unroll
      for (int j = 0; j < 4; ++j) {
        const int i = tid * 4 + j * 1024;
        if (i < NE) *(u32x2*)&ibuf[nxt][i / HH][i % HH] = pack4(pr[j]);
      }
    }
    if (layer == 0 && t + 1 < TTS && tid < BC) xin[nxt][tid] = px;

    if (batch_last) {
      __syncthreads();   // full drain: ALL waves' ring stores visible pre-flag
    } else {
      lds_barrier();     // LDS ordered; global stores remain in flight
    }

    // ---- flags (once per batch) ----
    if (batch_last && tid == 0) {
      if (layer < NL - 1)
        __hip_atomic_store(prog_out, t + 1, __ATOMIC_RELEASE, __HIP_MEMORY_SCOPE_AGENT);
      if (layer > 0)
        __hip_atomic_store(cons_in, t + 1, __ATOMIC_RELAXED, __HIP_MEMORY_SCOPE_AGENT);
    }

    // ---- layer-9 output dot (reads fresh hbuf[nxt], reconstruct bf16) ----
    if (layer == NL - 1) {
      const int b = tid >> 3, seg = tid & 7;
      float s = 0.f;
      #pragma unroll
      for (int jj = 0; jj < 13; ++jj) {
        const int j = seg * 13 + jj;
        if (j < HH) {
          float h = __uint_as_float((unsigned)hbuf[nxt][b][j] << 16);
          s += h * wouts[j];
        }
      }
      s += __shfl_xor(s, 1, 8);
      s += __shfl_xor(s, 2, 8);
      s += __shfl_xor(s, 4, 8);
      dso = s + boutv;
      if (t < TTS - 1) have_out_def = true;
    }
    if (layer < NL - 1 && !batch_last) have_ring_def = true;
  }

  // flush last layer-9 outputs (t = TTS-1)
  if (layer == NL - 1 && (tid & 7) == 0)
    out[(size_t)(chunk * BC + (tid >> 3)) * TTS + (TTS - 1)] = dso;
}

extern "C" void kernel_launch(void* const* d_in, const int* in_sizes, int n_in,
                              void* d_out, int out_size, void* d_ws, size_t ws_size,
                              hipStream_t stream) {
  const float* x    = (const float*)d_in[0];
  const float* h0   = (const float*)d_in[1];
  const float* Wih0 = (const float*)d_in[2];
  const float* Wih  = (const float*)d_in[3];
  const float* Whh  = (const float*)d_in[4];
  const float* bih  = (const float*)d_in[5];
  const float* bhh  = (const float*)d_in[6];
  const float* Wout = (const float*)d_in[7];
  const float* bout = (const float*)d_in[8];
  float* out = (float*)d_out;

  int*   wsi  = (int*)d_ws;
  float* ring = (float*)((char*)d_ws + 65536);

  // Pick deepest ring that fits ws: ring bytes = 9*16 * RD * 12800
  const size_t slot_bytes = (size_t)BC * HH * 4;   // 12800
  int RDv = 32;
  while (RDv > 2 && 65536 + (size_t)(NL - 1) * NB * RDv * slot_bytes > ws_size)
    RDv >>= 1;
  int Kv = RDv / 2;

  hipLaunchKernelGGL(init_ws_kernel, dim3(64), dim3(256), 0, stream, wsi);
  hipLaunchKernelGGL(rnn_pipe, dim3(NL * NB), dim3(NT), 0, stream,
                     x, h0, Wih0, Wih, Whh, bih, bhh, Wout, bout, out, ring, wsi,
                     Kv, RDv);
}

// Round 2
// 1962.152 us; speedup vs baseline: 1.2286x; 1.2286x over previous
//
#include <hip/hip_runtime.h>

// Multi-layer tanh RNN, layer-pipelined persistent kernel.
// R18 = R16 revert (BC=16/NB=32, 2 blk/CU — R17's 1 blk/CU lost the
// co-residency latency hiding, 1372->2411us) + RD=8/K=4 ring shrink.
//  Theory: R16's WRITE_SIZE 956MB == total ring store bytes (9*32*512*6400B)
//  -> ring writes ALL missed L2 (active window 7.4MB/XCD > 4MB L2 at RD=32).
//  RD=8 makes the ring window 1.84MB/XCD -> L2-resident: ring reads/writes
//  become L2 hits (200cyc vs L3 ~500cyc on the staging path), 1.4GB of L3
//  round-trip traffic disappears. K=4 also cuts pipeline fill 144->36 steps
//  (critical path 656->548). Handoff every 4 steps costs ~150cyc/step extra;
//  net predicted win ~20%.
// Everything else identical to R16: bf16 LDS state, fp32 ring, 2-plane
// weights, deferred stores, agent-scope flag protocol.

#define HH   100   // hidden
#define HS   132   // padded fp32 stride (bias etc.)
#define HSS  136   // bf16 LDS row stride in shorts (272B = 17*16, b128-aligned)
#define NL   10    // layers
#define BBS  512   // batch
#define TTS  512   // time
#define NB   32    // batch chunks
#define BC   16    // batch per chunk
#define NT   256   // threads per block

typedef __attribute__((ext_vector_type(8))) short short8;
typedef __attribute__((ext_vector_type(4))) float f32x4;
typedef __attribute__((ext_vector_type(2))) unsigned int u32x2;

__global__ void init_ws_kernel(int* wsi) {
  int i = blockIdx.x * blockDim.x + threadIdx.x;
  if (i < 16384) wsi[i] = 0;   // zero both flag regions (64KB)
}

__device__ __forceinline__ int flag_idx(int iface, int chunk) {
  return (iface * NB + chunk) * 16;
}

__device__ __forceinline__ void lds_barrier() {
  __asm__ __volatile__("s_waitcnt lgkmcnt(0)\n\ts_barrier" ::: "memory");
}
__device__ __forceinline__ void ctl_barrier() {
  __asm__ __volatile__("s_barrier" ::: "memory");
}

__device__ __forceinline__ float fast_tanh(float v) {
  float e = __expf(2.0f * v);
  return 1.0f - 2.0f * __builtin_amdgcn_rcpf(e + 1.0f);
}

__device__ __forceinline__ unsigned short bf_rtn(float x) {
  return (unsigned short)((__float_as_uint(x) + 0x8000u) >> 16);
}
__device__ __forceinline__ unsigned pack_rtn(float x0, float x1) {
  unsigned u0 = __float_as_uint(x0) + 0x8000u;
  unsigned u1 = __float_as_uint(x1) + 0x8000u;
  return (u0 >> 16) | (u1 & 0xFFFF0000u);
}
// f32x4 -> 4 bf16 packed in 8 bytes
__device__ __forceinline__ u32x2 pack4(f32x4 q) {
  u32x2 d;
  d[0] = pack_rtn(q[0], q[1]);
  d[1] = pack_rtn(q[2], q[3]);
  return d;
}

__global__ __launch_bounds__(NT, 2) void rnn_pipe(
    const float* __restrict__ x,     // [B,T,1]
    const float* __restrict__ h0,    // [L,B,H]
    const float* __restrict__ Wih0,  // [H,1]
    const float* __restrict__ Wih,   // [L-1,H,H]
    const float* __restrict__ Whh,   // [L,H,H]
    const float* __restrict__ bih,   // [L,H]
    const float* __restrict__ bhh,   // [L,H]
    const float* __restrict__ Wout,  // [1,H]
    const float* __restrict__ bout,  // [1]
    float* __restrict__ out,         // [B*T] outs ++ [L*B*H] h_final
    float* __restrict__ ring,
    int*   __restrict__ wsi,
    int Kv, int RDv)
{
  const int layer = blockIdx.x / NB;
  const int chunk = blockIdx.x % NB;
  const int tid   = threadIdx.x;
  const int Km = Kv - 1, RDm = RDv - 1;
  const int NE = BC * HH;  // 1600 elements per activation slot

  const int wave = tid >> 6, lane = tid & 63;
  const int quad = lane >> 4, lp = lane & 15;

  // LDS: 4*16*136*2 = 17.4KB state + ~1.7KB consts
  __shared__ unsigned short hbuf[2][BC][HSS];  // recurrent state bf16
  __shared__ unsigned short ibuf[2][BC][HSS];  // staged prev-layer input bf16
  __shared__ float bias[HS];
  __shared__ float wi0s[HS];
  __shared__ float wouts[HS];
  __shared__ float xin[2][BC];

  // ---- one-time LDS init ----
  for (int i = tid; i < 2 * BC * HSS; i += NT) {
    (&hbuf[0][0][0])[i] = 0; (&ibuf[0][0][0])[i] = 0;
  }
  for (int i = tid; i < HS; i += NT) {
    bias[i]  = (i < HH) ? (bih[layer * HH + i] + bhh[layer * HH + i]) : 0.f;
    wi0s[i]  = (i < HH) ? Wih0[i] : 0.f;
    wouts[i] = (i < HH) ? Wout[i] : 0.f;
  }
  if (tid < BC) { xin[0][tid] = 0.f; xin[1][tid] = 0.f; }
  __syncthreads();
  for (int idx = tid; idx < NE; idx += NT)
    hbuf[0][idx / HH][idx % HH] =
        bf_rtn(h0[((size_t)layer * BBS + chunk * BC + idx / HH) * HH + idx % HH]);
  __syncthreads();

  // ---- B-fragments in registers: fused W = [Whh (k 0..99) ; Wih (k 128..227)]
  // 2-plane (weight precision kept), 128 VGPRs.
  short8 Bf[8][2][2];
  #pragma unroll
  for (int kc = 0; kc < 8; ++kc) {
    #pragma unroll
    for (int ntl = 0; ntl < 2; ++ntl) {
      const int n = wave * 32 + ntl * 16 + lp;
      float wv[8];
      #pragma unroll
      for (int j = 0; j < 8; ++j) {
        const int k = kc * 32 + quad * 8 + j;
        float w = 0.f;
        if (kc < 4) {
          if (k < HH && n < HH) w = Whh[(size_t)layer * HH * HH + n * HH + k];
        } else {
          const int kk = k - 128;
          if (layer > 0 && kk >= 0 && kk < HH && n < HH)
            w = Wih[(size_t)(layer - 1) * HH * HH + n * HH + kk];
        }
        wv[j] = w;
      }
      // plane1 = truncate, plane2 = residual (exact split)
      __attribute__((ext_vector_type(4))) unsigned int p1, p2;
      #pragma unroll
      for (int j2 = 0; j2 < 4; ++j2) {
        unsigned ua = __float_as_uint(wv[2 * j2]), ub = __float_as_uint(wv[2 * j2 + 1]);
        p1[j2] = (ua >> 16) | (ub & 0xFFFF0000u);
        float ra = wv[2 * j2]     - __uint_as_float(ua & 0xFFFF0000u);
        float rb = wv[2 * j2 + 1] - __uint_as_float(ub & 0xFFFF0000u);
        p2[j2] = (__float_as_uint(ra) >> 16) | (__float_as_uint(rb) & 0xFFFF0000u);
      }
      Bf[kc][ntl][0] = __builtin_bit_cast(short8, p1);
      Bf[kc][ntl][1] = __builtin_bit_cast(short8, p2);
    }
  }

  // ---- flags / ring pointers (R8-proven protocol, agent scope) ----
  int* prog_in  = (layer > 0)      ? wsi + flag_idx(layer - 1, chunk)        : nullptr;
  int* cons_in  = (layer > 0)      ? wsi + 8192 + flag_idx(layer - 1, chunk) : nullptr;
  int* prog_out = (layer < NL - 1) ? wsi + flag_idx(layer, chunk)            : nullptr;
  int* cons_out = (layer < NL - 1) ? wsi + 8192 + flag_idx(layer, chunk)     : nullptr;
  const size_t slot_sz = (size_t)NE;  // 1600 floats
  float* ring_in  = (layer > 0)      ? ring + (size_t)((layer - 1) * NB + chunk) * RDv * slot_sz : nullptr;
  float* ring_out = (layer < NL - 1) ? ring + (size_t)(layer * NB + chunk) * RDv * slot_sz       : nullptr;

  const int jcv[2] = { wave * 32 + lp, wave * 32 + 16 + lp };   // C columns
  const float br[2]  = { bias[jcv[0]], bias[jcv[1]] };
  const float w0r[2] = { wi0s[jcv[0]], wi0s[jcv[1]] };
  const float boutv = bout[0];

  f32x4 hreg[2];             // step-t h values fp32 (deferred ring stores)
  float dso = 0.f;           // deferred layer-9 output
  float px = 0.f;
  bool have_ring_def = false, have_out_def = false;

  for (int t = 0; t < TTS; ++t) {
    const int par = t & 1, nxt = par ^ 1;
    const bool batch_start = (t & Km) == 0;
    const bool batch_last  = (t & Km) == Km;

    // ---- batch boundary: wait + exposed staging of slot t into parity par ----
    if (batch_start) {
      if (tid == 0) {
        if (layer > 0) {
          while (__hip_atomic_load(prog_in, __ATOMIC_RELAXED, __HIP_MEMORY_SCOPE_AGENT) < t + Kv)
            __builtin_amdgcn_s_sleep(1);
          (void)__hip_atomic_load(prog_in, __ATOMIC_ACQUIRE, __HIP_MEMORY_SCOPE_AGENT);
        }
        if (layer < NL - 1 && t + Kv > RDv) {
          while (__hip_atomic_load(cons_out, __ATOMIC_RELAXED, __HIP_MEMORY_SCOPE_AGENT) < t + Kv - RDv)
            __builtin_amdgcn_s_sleep(1);
        }
      }
      ctl_barrier();
      if (layer > 0) {
        const float* src = ring_in + (size_t)(t & RDm) * slot_sz;
        int i0 = tid * 4;
        if (i0 < NE) {
          u32x2 d = pack4(*(const f32x4*)(src + i0));
          *(u32x2*)&ibuf[par][i0 / HH][i0 % HH] = d;
        }
        int i1 = i0 + 1024;
        if (i1 < NE) {
          u32x2 d = pack4(*(const f32x4*)(src + i1));
          *(u32x2*)&ibuf[par][i1 / HH][i1 % HH] = d;
        }
      } else if (t == 0) {
        if (tid < BC) xin[0][tid] = x[(size_t)(chunk * BC + tid) * TTS];
      }
      lds_barrier();
    }

    // ---- issue deferred stores from step t-1 (stay in flight past barrier) ----
    if (have_ring_def) {
      float* dst = ring_out + (size_t)((t - 1) & RDm) * slot_sz;
      #pragma unroll
      for (int ntl = 0; ntl < 2; ++ntl)
        if (jcv[ntl] < HH)
          #pragma unroll
          for (int r = 0; r < 4; ++r)
            dst[(size_t)(quad * 4 + r) * HH + jcv[ntl]] = hreg[ntl][r];
      have_ring_def = false;
    }
    if (have_out_def) {
      if ((tid & 15) == 0)
        out[(size_t)(chunk * BC + (tid >> 4)) * TTS + (t - 1)] = dso;
      have_out_def = false;
    }

    // ---- prefetch inp_{t+1} into regs (staged into ibuf[nxt] post-compute) ----
    f32x4 p0 = {}, p1 = {};
    bool pre = false;
    if (layer > 0) {
      if (!batch_last && t + 1 < TTS) {
        const float* src = ring_in + (size_t)((t + 1) & RDm) * slot_sz;
        int i0 = tid * 4;
        if (i0 < NE) p0 = *(const f32x4*)(src + i0);
        if (i0 + 1024 < NE) p1 = *(const f32x4*)(src + i0 + 1024);
        pre = true;
      }
    } else {
      if (t + 1 < TTS && tid < BC) px = x[(size_t)(chunk * BC + tid) * TTS + (t + 1)];
    }

    // ---- MFMA: A = direct bf16 ds_read_b128, B 2-plane -> 2 MFMAs per kc ----
    f32x4 acc[2] = {}, acc2[2] = {};
    auto mfma_kc = [&](f32x4* accp, const unsigned short (*buf)[HSS], int koff, int bfi) {
      short8 A1 = *(const short8*)&buf[lp][koff + quad * 8];
      #pragma unroll
      for (int ntl = 0; ntl < 2; ++ntl) {
        accp[ntl] = __builtin_amdgcn_mfma_f32_16x16x32_bf16(
            A1, Bf[bfi][ntl][1], accp[ntl], 0, 0, 0);   // a1*b2 (small first)
        accp[ntl] = __builtin_amdgcn_mfma_f32_16x16x32_bf16(
            A1, Bf[bfi][ntl][0], accp[ntl], 0, 0, 0);   // a1*b1
      }
    };
    #pragma unroll
    for (int kc = 0; kc < 4; ++kc) mfma_kc(acc, hbuf[par], kc * 32, kc);
    if (layer > 0) {
      #pragma unroll
      for (int kc = 0; kc < 4; ++kc) mfma_kc(acc2, ibuf[par], kc * 32, kc + 4);
    }

    // ---- epilogue: merge, bias(+x*w0), tanh, pack bf16, write hbuf[nxt] ----
    #pragma unroll
    for (int ntl = 0; ntl < 2; ++ntl) {
      #pragma unroll
      for (int r = 0; r < 4; ++r) {
        const int m = quad * 4 + r;
        float v = acc[ntl][r] + acc2[ntl][r] + br[ntl];
        if (layer == 0) v += xin[par][m] * w0r[ntl];
        float h = fast_tanh(v);
        hreg[ntl][r] = h;
        if (jcv[ntl] < HH) hbuf[nxt][m][jcv[ntl]] = bf_rtn(h);
      }
    }

    // batch-last ring store cannot be deferred past the flag publish
    if (layer < NL - 1 && batch_last) {
      float* dst = ring_out + (size_t)(t & RDm) * slot_sz;
      #pragma unroll
      for (int ntl = 0; ntl < 2; ++ntl)
        if (jcv[ntl] < HH)
          #pragma unroll
          for (int r = 0; r < 4; ++r)
            dst[(size_t)(quad * 4 + r) * HH + jcv[ntl]] = hreg[ntl][r];
    }
    if (t == TTS - 1) {   // final hidden state, fp32-exact from registers
      #pragma unroll
      for (int ntl = 0; ntl < 2; ++ntl)
        if (jcv[ntl] < HH)
          #pragma unroll
          for (int r = 0; r < 4; ++r)
            out[(size_t)BBS * TTS +
                ((size_t)layer * BBS + chunk * BC + quad * 4 + r) * HH + jcv[ntl]] =
                hreg[ntl][r];
    }

    // ---- stage prefetched inp_{t+1} into ibuf[nxt] / xin[nxt] ----
    if (pre) {
      int i0 = tid * 4;
      if (i0 < NE) *(u32x2*)&ibuf[nxt][i0 / HH][i0 % HH] = pack4(p0);
      int i1 = i0 + 1024;
      if (i1 < NE) *(u32x2*)&ibuf[nxt][i1 / HH][i1 % HH] = pack4(p1);
    }
    if (layer == 0 && t + 1 < TTS && tid < BC) xin[nxt][tid] = px;

    if (batch_last) {
      __syncthreads();   // full drain: ALL waves' ring stores visible pre-flag
    } else {
      lds_barrier();     // LDS ordered; global stores remain in flight
    }

    // ---- flags (once per batch) ----
    if (batch_last && tid == 0) {
      if (layer < NL - 1)
        __hip_atomic_store(prog_out, t + 1, __ATOMIC_RELEASE, __HIP_MEMORY_SCOPE_AGENT);
      if (layer > 0)
        __hip_atomic_store(cons_in, t + 1, __ATOMIC_RELAXED, __HIP_MEMORY_SCOPE_AGENT);
    }

    // ---- layer-9 output dot (reads fresh hbuf[nxt], reconstruct bf16) ----
    if (layer == NL - 1) {
      const int b = tid >> 4, seg = tid & 15;
      float s = 0.f;
      #pragma unroll
      for (int jj = 0; jj < 7; ++jj) {
        const int j = seg * 7 + jj;
        if (j < HH) {
          float h = __uint_as_float((unsigned)hbuf[nxt][b][j] << 16);
          s += h * wouts[j];
        }
      }
      s += __shfl_xor(s, 1, 16);
      s += __shfl_xor(s, 2, 16);
      s += __shfl_xor(s, 4, 16);
      s += __shfl_xor(s, 8, 16);
      dso = s + boutv;
      if (t < TTS - 1) have_out_def = true;
    }
    if (layer < NL - 1 && !batch_last) have_ring_def = true;
  }

  // flush last layer-9 outputs (t = TTS-1)
  if (layer == NL - 1 && (tid & 15) == 0)
    out[(size_t)(chunk * BC + (tid >> 4)) * TTS + (TTS - 1)] = dso;
}

extern "C" void kernel_launch(void* const* d_in, const int* in_sizes, int n_in,
                              void* d_out, int out_size, void* d_ws, size_t ws_size,
                              hipStream_t stream) {
  const float* x    = (const float*)d_in[0];
  const float* h0   = (const float*)d_in[1];
  const float* Wih0 = (const float*)d_in[2];
  const float* Wih  = (const float*)d_in[3];
  const float* Whh  = (const float*)d_in[4];
  const float* bih  = (const float*)d_in[5];
  const float* bhh  = (const float*)d_in[6];
  const float* Wout = (const float*)d_in[7];
  const float* bout = (const float*)d_in[8];
  float* out = (float*)d_out;

  int*   wsi  = (int*)d_ws;
  float* ring = (float*)((char*)d_ws + 65536);

  // RD=8: ring = 9*32 * 8 * 6400B = 14.75MB total -> 1.84MB/XCD active
  // window, L2-resident (the R18 point). Shrink further only if ws is tiny.
  const size_t slot_bytes = (size_t)BC * HH * 4;   // 6400
  int RDv = 8;
  while (RDv > 2 && 65536 + (size_t)(NL - 1) * NB * RDv * slot_bytes > ws_size)
    RDv >>= 1;
  int Kv = RDv / 2;

  hipLaunchKernelGGL(init_ws_kernel, dim3(64), dim3(256), 0, stream, wsi);
  hipLaunchKernelGGL(rnn_pipe, dim3(NL * NB), dim3(NT), 0, stream,
                     x, h0, Wih0, Wih, Whh, bih, bhh, Wout, bout, out, ring, wsi,
                     Kv, RDv);
}

// Round 3
// 1363.149 us; speedup vs baseline: 1.7685x; 1.4394x over previous
//
#include <hip/hip_runtime.h>

// Multi-layer tanh RNN, layer-pipelined persistent kernel.
// R19 = R16 core (BC=16/NB=32, RD=32 deep ring — best, 1372us) + two changes:
//  (a) A-fragment hoist + split MFMA chains: all 8 ds_read_b128 issued before
//      any MFMA (LDS latency exposed once, not 8x), and accumulation split
//      into per-plane 4-deep chains merged by VALU adds (was 8-deep).
//      Theory: R16 vs R17 instr-count scaling shows the step wall is a
//      serialized latency chain (~28 cyc/instr); the read->4xMFMA->read
//      pattern exposes ~120cyc LDS latency up to 8x/step.
//  (b) K=8 with RD=32: pipeline fill 9K = 144 -> 72 step-times (-22%->-11%
//      of total), while slack RD-K RISES 16->24 steps. R18 lesson: K=4/RD=8
//      failed from slack collapse + handoff frequency, NOT ring traffic
//      (FETCH 411->18MB proved reads L2-hit yet dur got worse).
// Everything else identical to R16: bf16 LDS state, fp32 ring, 2-plane
// weights, deferred stores, agent-scope flag protocol, 2 blk/CU.

#define HH   100   // hidden
#define HS   132   // padded fp32 stride (bias etc.)
#define HSS  136   // bf16 LDS row stride in shorts (272B = 17*16, b128-aligned)
#define NL   10    // layers
#define BBS  512   // batch
#define TTS  512   // time
#define NB   32    // batch chunks
#define BC   16    // batch per chunk
#define NT   256   // threads per block

typedef __attribute__((ext_vector_type(8))) short short8;
typedef __attribute__((ext_vector_type(4))) float f32x4;
typedef __attribute__((ext_vector_type(2))) unsigned int u32x2;

__global__ void init_ws_kernel(int* wsi) {
  int i = blockIdx.x * blockDim.x + threadIdx.x;
  if (i < 16384) wsi[i] = 0;   // zero both flag regions (64KB)
}

__device__ __forceinline__ int flag_idx(int iface, int chunk) {
  return (iface * NB + chunk) * 16;
}

__device__ __forceinline__ void lds_barrier() {
  __asm__ __volatile__("s_waitcnt lgkmcnt(0)\n\ts_barrier" ::: "memory");
}
__device__ __forceinline__ void ctl_barrier() {
  __asm__ __volatile__("s_barrier" ::: "memory");
}

__device__ __forceinline__ float fast_tanh(float v) {
  float e = __expf(2.0f * v);
  return 1.0f - 2.0f * __builtin_amdgcn_rcpf(e + 1.0f);
}

__device__ __forceinline__ unsigned short bf_rtn(float x) {
  return (unsigned short)((__float_as_uint(x) + 0x8000u) >> 16);
}
__device__ __forceinline__ unsigned pack_rtn(float x0, float x1) {
  unsigned u0 = __float_as_uint(x0) + 0x8000u;
  unsigned u1 = __float_as_uint(x1) + 0x8000u;
  return (u0 >> 16) | (u1 & 0xFFFF0000u);
}
// f32x4 -> 4 bf16 packed in 8 bytes
__device__ __forceinline__ u32x2 pack4(f32x4 q) {
  u32x2 d;
  d[0] = pack_rtn(q[0], q[1]);
  d[1] = pack_rtn(q[2], q[3]);
  return d;
}

__global__ __launch_bounds__(NT, 2) void rnn_pipe(
    const float* __restrict__ x,     // [B,T,1]
    const float* __restrict__ h0,    // [L,B,H]
    const float* __restrict__ Wih0,  // [H,1]
    const float* __restrict__ Wih,   // [L-1,H,H]
    const float* __restrict__ Whh,   // [L,H,H]
    const float* __restrict__ bih,   // [L,H]
    const float* __restrict__ bhh,   // [L,H]
    const float* __restrict__ Wout,  // [1,H]
    const float* __restrict__ bout,  // [1]
    float* __restrict__ out,         // [B*T] outs ++ [L*B*H] h_final
    float* __restrict__ ring,
    int*   __restrict__ wsi,
    int Kv, int RDv)
{
  const int layer = blockIdx.x / NB;
  const int chunk = blockIdx.x % NB;
  const int tid   = threadIdx.x;
  const int Km = Kv - 1, RDm = RDv - 1;
  const int NE = BC * HH;  // 1600 elements per activation slot

  const int wave = tid >> 6, lane = tid & 63;
  const int quad = lane >> 4, lp = lane & 15;

  // LDS: 4*16*136*2 = 17.4KB state + ~1.7KB consts
  __shared__ unsigned short hbuf[2][BC][HSS];  // recurrent state bf16
  __shared__ unsigned short ibuf[2][BC][HSS];  // staged prev-layer input bf16
  __shared__ float bias[HS];
  __shared__ float wi0s[HS];
  __shared__ float wouts[HS];
  __shared__ float xin[2][BC];

  // ---- one-time LDS init ----
  for (int i = tid; i < 2 * BC * HSS; i += NT) {
    (&hbuf[0][0][0])[i] = 0; (&ibuf[0][0][0])[i] = 0;
  }
  for (int i = tid; i < HS; i += NT) {
    bias[i]  = (i < HH) ? (bih[layer * HH + i] + bhh[layer * HH + i]) : 0.f;
    wi0s[i]  = (i < HH) ? Wih0[i] : 0.f;
    wouts[i] = (i < HH) ? Wout[i] : 0.f;
  }
  if (tid < BC) { xin[0][tid] = 0.f; xin[1][tid] = 0.f; }
  __syncthreads();
  for (int idx = tid; idx < NE; idx += NT)
    hbuf[0][idx / HH][idx % HH] =
        bf_rtn(h0[((size_t)layer * BBS + chunk * BC + idx / HH) * HH + idx % HH]);
  __syncthreads();

  // ---- B-fragments in registers: fused W = [Whh (k 0..99) ; Wih (k 128..227)]
  // 2-plane (weight precision kept), 128 VGPRs.
  short8 Bf[8][2][2];
  #pragma unroll
  for (int kc = 0; kc < 8; ++kc) {
    #pragma unroll
    for (int ntl = 0; ntl < 2; ++ntl) {
      const int n = wave * 32 + ntl * 16 + lp;
      float wv[8];
      #pragma unroll
      for (int j = 0; j < 8; ++j) {
        const int k = kc * 32 + quad * 8 + j;
        float w = 0.f;
        if (kc < 4) {
          if (k < HH && n < HH) w = Whh[(size_t)layer * HH * HH + n * HH + k];
        } else {
          const int kk = k - 128;
          if (layer > 0 && kk >= 0 && kk < HH && n < HH)
            w = Wih[(size_t)(layer - 1) * HH * HH + n * HH + kk];
        }
        wv[j] = w;
      }
      // plane1 = truncate, plane2 = residual (exact split)
      __attribute__((ext_vector_type(4))) unsigned int p1, p2;
      #pragma unroll
      for (int j2 = 0; j2 < 4; ++j2) {
        unsigned ua = __float_as_uint(wv[2 * j2]), ub = __float_as_uint(wv[2 * j2 + 1]);
        p1[j2] = (ua >> 16) | (ub & 0xFFFF0000u);
        float ra = wv[2 * j2]     - __uint_as_float(ua & 0xFFFF0000u);
        float rb = wv[2 * j2 + 1] - __uint_as_float(ub & 0xFFFF0000u);
        p2[j2] = (__float_as_uint(ra) >> 16) | (__float_as_uint(rb) & 0xFFFF0000u);
      }
      Bf[kc][ntl][0] = __builtin_bit_cast(short8, p1);
      Bf[kc][ntl][1] = __builtin_bit_cast(short8, p2);
    }
  }

  // ---- flags / ring pointers (R8-proven protocol, agent scope) ----
  int* prog_in  = (layer > 0)      ? wsi + flag_idx(layer - 1, chunk)        : nullptr;
  int* cons_in  = (layer > 0)      ? wsi + 8192 + flag_idx(layer - 1, chunk) : nullptr;
  int* prog_out = (layer < NL - 1) ? wsi + flag_idx(layer, chunk)            : nullptr;
  int* cons_out = (layer < NL - 1) ? wsi + 8192 + flag_idx(layer, chunk)     : nullptr;
  const size_t slot_sz = (size_t)NE;  // 1600 floats
  float* ring_in  = (layer > 0)      ? ring + (size_t)((layer - 1) * NB + chunk) * RDv * slot_sz : nullptr;
  float* ring_out = (layer < NL - 1) ? ring + (size_t)(layer * NB + chunk) * RDv * slot_sz       : nullptr;

  const int jcv[2] = { wave * 32 + lp, wave * 32 + 16 + lp };   // C columns
  const float br[2]  = { bias[jcv[0]], bias[jcv[1]] };
  const float w0r[2] = { wi0s[jcv[0]], wi0s[jcv[1]] };
  const float boutv = bout[0];

  f32x4 hreg[2];             // step-t h values fp32 (deferred ring stores)
  float dso = 0.f;           // deferred layer-9 output
  float px = 0.f;
  bool have_ring_def = false, have_out_def = false;

  for (int t = 0; t < TTS; ++t) {
    const int par = t & 1, nxt = par ^ 1;
    const bool batch_start = (t & Km) == 0;
    const bool batch_last  = (t & Km) == Km;

    // ---- batch boundary: wait + exposed staging of slot t into parity par ----
    if (batch_start) {
      if (tid == 0) {
        if (layer > 0) {
          while (__hip_atomic_load(prog_in, __ATOMIC_RELAXED, __HIP_MEMORY_SCOPE_AGENT) < t + Kv)
            __builtin_amdgcn_s_sleep(1);
          (void)__hip_atomic_load(prog_in, __ATOMIC_ACQUIRE, __HIP_MEMORY_SCOPE_AGENT);
        }
        if (layer < NL - 1 && t + Kv > RDv) {
          while (__hip_atomic_load(cons_out, __ATOMIC_RELAXED, __HIP_MEMORY_SCOPE_AGENT) < t + Kv - RDv)
            __builtin_amdgcn_s_sleep(1);
        }
      }
      ctl_barrier();
      if (layer > 0) {
        const float* src = ring_in + (size_t)(t & RDm) * slot_sz;
        int i0 = tid * 4;
        if (i0 < NE) {
          u32x2 d = pack4(*(const f32x4*)(src + i0));
          *(u32x2*)&ibuf[par][i0 / HH][i0 % HH] = d;
        }
        int i1 = i0 + 1024;
        if (i1 < NE) {
          u32x2 d = pack4(*(const f32x4*)(src + i1));
          *(u32x2*)&ibuf[par][i1 / HH][i1 % HH] = d;
        }
      } else if (t == 0) {
        if (tid < BC) xin[0][tid] = x[(size_t)(chunk * BC + tid) * TTS];
      }
      lds_barrier();
    }

    // ---- A-fragments: hoist ALL LDS reads ahead of stores/MFMAs ----
    short8 Ah[4], Ai[4];
    #pragma unroll
    for (int kc = 0; kc < 4; ++kc)
      Ah[kc] = *(const short8*)&hbuf[par][lp][kc * 32 + quad * 8];
    if (layer > 0) {
      #pragma unroll
      for (int kc = 0; kc < 4; ++kc)
        Ai[kc] = *(const short8*)&ibuf[par][lp][kc * 32 + quad * 8];
    } else {
      #pragma unroll
      for (int kc = 0; kc < 4; ++kc) Ai[kc] = short8{};
    }

    // ---- issue deferred stores from step t-1 (stay in flight past barrier) ----
    if (have_ring_def) {
      float* dst = ring_out + (size_t)((t - 1) & RDm) * slot_sz;
      #pragma unroll
      for (int ntl = 0; ntl < 2; ++ntl)
        if (jcv[ntl] < HH)
          #pragma unroll
          for (int r = 0; r < 4; ++r)
            dst[(size_t)(quad * 4 + r) * HH + jcv[ntl]] = hreg[ntl][r];
      have_ring_def = false;
    }
    if (have_out_def) {
      if ((tid & 15) == 0)
        out[(size_t)(chunk * BC + (tid >> 4)) * TTS + (t - 1)] = dso;
      have_out_def = false;
    }

    // ---- prefetch inp_{t+1} into regs (staged into ibuf[nxt] post-compute) ----
    f32x4 p0 = {}, p1 = {};
    bool pre = false;
    if (layer > 0) {
      if (!batch_last && t + 1 < TTS) {
        const float* src = ring_in + (size_t)((t + 1) & RDm) * slot_sz;
        int i0 = tid * 4;
        if (i0 < NE) p0 = *(const f32x4*)(src + i0);
        if (i0 + 1024 < NE) p1 = *(const f32x4*)(src + i0 + 1024);
        pre = true;
      }
    } else {
      if (t + 1 < TTS && tid < BC) px = x[(size_t)(chunk * BC + tid) * TTS + (t + 1)];
    }

    // ---- MFMA: split per-plane chains (4-deep each), merged by VALU adds ----
    f32x4 a1[2] = {}, a2[2] = {};   // hbuf part: plane1 / plane2 chains
    f32x4 c1[2] = {}, c2[2] = {};   // ibuf part
    #pragma unroll
    for (int kc = 0; kc < 4; ++kc) {
      #pragma unroll
      for (int ntl = 0; ntl < 2; ++ntl) {
        a2[ntl] = __builtin_amdgcn_mfma_f32_16x16x32_bf16(Ah[kc], Bf[kc][ntl][1], a2[ntl], 0, 0, 0);
        a1[ntl] = __builtin_amdgcn_mfma_f32_16x16x32_bf16(Ah[kc], Bf[kc][ntl][0], a1[ntl], 0, 0, 0);
      }
    }
    if (layer > 0) {
      #pragma unroll
      for (int kc = 0; kc < 4; ++kc) {
        #pragma unroll
        for (int ntl = 0; ntl < 2; ++ntl) {
          c2[ntl] = __builtin_amdgcn_mfma_f32_16x16x32_bf16(Ai[kc], Bf[kc + 4][ntl][1], c2[ntl], 0, 0, 0);
          c1[ntl] = __builtin_amdgcn_mfma_f32_16x16x32_bf16(Ai[kc], Bf[kc + 4][ntl][0], c1[ntl], 0, 0, 0);
        }
      }
    }

    // ---- epilogue: merge, bias(+x*w0), tanh, pack bf16, write hbuf[nxt] ----
    #pragma unroll
    for (int ntl = 0; ntl < 2; ++ntl) {
      f32x4 sum = (a1[ntl] + a2[ntl]) + (c1[ntl] + c2[ntl]);
      #pragma unroll
      for (int r = 0; r < 4; ++r) {
        const int m = quad * 4 + r;
        float v = sum[r] + br[ntl];
        if (layer == 0) v += xin[par][m] * w0r[ntl];
        float h = fast_tanh(v);
        hreg[ntl][r] = h;
        if (jcv[ntl] < HH) hbuf[nxt][m][jcv[ntl]] = bf_rtn(h);
      }
    }

    // batch-last ring store cannot be deferred past the flag publish
    if (layer < NL - 1 && batch_last) {
      float* dst = ring_out + (size_t)(t & RDm) * slot_sz;
      #pragma unroll
      for (int ntl = 0; ntl < 2; ++ntl)
        if (jcv[ntl] < HH)
          #pragma unroll
          for (int r = 0; r < 4; ++r)
            dst[(size_t)(quad * 4 + r) * HH + jcv[ntl]] = hreg[ntl][r];
    }
    if (t == TTS - 1) {   // final hidden state, fp32-exact from registers
      #pragma unroll
      for (int ntl = 0; ntl < 2; ++ntl)
        if (jcv[ntl] < HH)
          #pragma unroll
          for (int r = 0; r < 4; ++r)
            out[(size_t)BBS * TTS +
                ((size_t)layer * BBS + chunk * BC + quad * 4 + r) * HH + jcv[ntl]] =
                hreg[ntl][r];
    }

    // ---- stage prefetched inp_{t+1} into ibuf[nxt] / xin[nxt] ----
    if (pre) {
      int i0 = tid * 4;
      if (i0 < NE) *(u32x2*)&ibuf[nxt][i0 / HH][i0 % HH] = pack4(p0);
      int i1 = i0 + 1024;
      if (i1 < NE) *(u32x2*)&ibuf[nxt][i1 / HH][i1 % HH] = pack4(p1);
    }
    if (layer == 0 && t + 1 < TTS && tid < BC) xin[nxt][tid] = px;

    if (batch_last) {
      __syncthreads();   // full drain: ALL waves' ring stores visible pre-flag
    } else {
      lds_barrier();     // LDS ordered; global stores remain in flight
    }

    // ---- flags (once per batch) ----
    if (batch_last && tid == 0) {
      if (layer < NL - 1)
        __hip_atomic_store(prog_out, t + 1, __ATOMIC_RELEASE, __HIP_MEMORY_SCOPE_AGENT);
      if (layer > 0)
        __hip_atomic_store(cons_in, t + 1, __ATOMIC_RELAXED, __HIP_MEMORY_SCOPE_AGENT);
    }

    // ---- layer-9 output dot (reads fresh hbuf[nxt], reconstruct bf16) ----
    if (layer == NL - 1) {
      const int b = tid >> 4, seg = tid & 15;
      float s = 0.f;
      #pragma unroll
      for (int jj = 0; jj < 7; ++jj) {
        const int j = seg * 7 + jj;
        if (j < HH) {
          float h = __uint_as_float((unsigned)hbuf[nxt][b][j] << 16);
          s += h * wouts[j];
        }
      }
      s += __shfl_xor(s, 1, 16);
      s += __shfl_xor(s, 2, 16);
      s += __shfl_xor(s, 4, 16);
      s += __shfl_xor(s, 8, 16);
      dso = s + boutv;
      if (t < TTS - 1) have_out_def = true;
    }
    if (layer < NL - 1 && !batch_last) have_ring_def = true;
  }

  // flush last layer-9 outputs (t = TTS-1)
  if (layer == NL - 1 && (tid & 15) == 0)
    out[(size_t)(chunk * BC + (tid >> 4)) * TTS + (TTS - 1)] = dso;
}

extern "C" void kernel_launch(void* const* d_in, const int* in_sizes, int n_in,
                              void* d_out, int out_size, void* d_ws, size_t ws_size,
                              hipStream_t stream) {
  const float* x    = (const float*)d_in[0];
  const float* h0   = (const float*)d_in[1];
  const float* Wih0 = (const float*)d_in[2];
  const float* Wih  = (const float*)d_in[3];
  const float* Whh  = (const float*)d_in[4];
  const float* bih  = (const float*)d_in[5];
  const float* bhh  = (const float*)d_in[6];
  const float* Wout = (const float*)d_in[7];
  const float* bout = (const float*)d_in[8];
  float* out = (float*)d_out;

  int*   wsi  = (int*)d_ws;
  float* ring = (float*)((char*)d_ws + 65536);

  // Deep ring RD=32 (slack), small batch K=8 (fill = 9*8 = 72 steps).
  // Slack RD-K = 24 steps (> R16's 16) -> jitter absorbed, unlike R18.
  const size_t slot_bytes = (size_t)BC * HH * 4;   // 6400
  int RDv = 32;
  while (RDv > 2 && 65536 + (size_t)(NL - 1) * NB * RDv * slot_bytes > ws_size)
    RDv >>= 1;
  int Kv = (RDv >= 16) ? 8 : RDv / 2;

  hipLaunchKernelGGL(init_ws_kernel, dim3(64), dim3(256), 0, stream, wsi);
  hipLaunchKernelGGL(rnn_pipe, dim3(NL * NB), dim3(NT), 0, stream,
                     x, h0, Wih0, Wih, Whh, bih, bhh, Wout, bout, out, ring, wsi,
                     Kv, RDv);
}